// Round 11
// baseline (144.943 us; speedup 1.0000x reference)
//
#include <hip/hip_runtime.h>
#include <hip/hip_bf16.h>

#define NA 4
#define BB 256
#define DDm 128
#define KKm 256   // hidden = 2*D

typedef __attribute__((ext_vector_type(4))) float f32x4;
typedef __attribute__((ext_vector_type(4))) unsigned int u32x4;
typedef __attribute__((ext_vector_type(8))) short bf16x8;

// RNE float -> bf16 bits
__device__ __forceinline__ unsigned int f2bf(float f) {
  unsigned int bits = __builtin_bit_cast(unsigned int, f);
  unsigned int lsb = (bits >> 16) & 1u;
  return (bits + 0x7fffu + lsb) >> 16;
}

// Swizzled byte offset of element (row a, col k) inside a [128][256] bf16 tile.
// Row stride 512B; XOR bits 4-6 with (a&7): conflict-free b128 column reads.
__device__ __forceinline__ int swz_off(int a, int k2bytes) {
  return ((a << 9) + k2bytes) ^ ((a & 7) << 4);
}

// prep: W1T fp32 [a][k] (coalesced phase-1 reads) + swizzled bf16 W1T tile.
__global__ __launch_bounds__(256) void prep_kernel(const float* __restrict__ W1,
                                                   unsigned short* __restrict__ Wt_g,
                                                   float* __restrict__ W1T) {
  int blk = blockIdx.x;          // 32 blocks = 4 agents x 8 chunks
  int i = blk >> 3;
  int chunk = blk & 7;
  const float* W1i = W1 + i * KKm * DDm;
  char* Wti = (char*)(Wt_g + i * 32768);
  float* W1Ti = W1T + i * DDm * KKm;
  int base = chunk * 4096;
  for (int idx = base + threadIdx.x; idx < base + 4096; idx += 256) {
    int a = idx >> 8;            // 0..127 (z-dim)
    int k = idx & 255;           // 0..255 (hidden)
    float v = W1i[k * DDm + a];
    W1Ti[a * KKm + k] = v;
    *(unsigned short*)(Wti + swz_off(a, k << 1)) = (unsigned short)f2bf(v);
  }
}

// Block = one (i,j) pair x 8 batches. 4 waves, ONE barrier. After it, each
// wave streams 4 independent jobs (one batch x 64 rows x 128 cols each):
// kc-loop (4 A-reads + 8 B-reads per kc -> 3B LDS-read per B output) then
// stores, which drain under the next job's compute. No further barriers.
__global__ __launch_bounds__(256, 2) void hess_kernel(
    const float* __restrict__ z_all, const float* __restrict__ b1,
    const float* __restrict__ W2, const unsigned short* __restrict__ Wt_g,
    const float* __restrict__ W1T, float* __restrict__ out) {
  __shared__ __align__(16) unsigned short Wt[32768];   // 64KB swizzled bf16 W1_i^T
  __shared__ __align__(16) float s_lds[8][KKm];        // 8KB: per-batch scale vectors

  int t = threadIdx.x;
  int blk = blockIdx.x;
  int pair = blk >> 5;            // 0..15
  int bgrp = blk & 31;            // batch group (8 batches)
  int i = pair >> 2;
  int j = pair & 3;

  if (i == j) {
    // zero 8 batches' diagonal blocks: 512KB contiguous
    f32x4* zp = (f32x4*)(out + (((size_t)pair * BB + bgrp * 8) << 14));
    f32x4 z4 = (f32x4){0.f, 0.f, 0.f, 0.f};
#pragma unroll
    for (int q = 0; q < 128; ++q) zp[q * 256 + t] = z4;
    return;
  }

  // --- issue async staging of W-tile (linear copy; swizzle pre-applied in global)
  {
    int wv = t >> 6, lane = t & 63;
    const char* src = (const char*)(Wt_g + i * 32768);
#pragma unroll
    for (int it = 0; it < 16; ++it) {
      int off = (it * 4 + wv) * 1024;
      __builtin_amdgcn_global_load_lds(
          (const __attribute__((address_space(1))) unsigned int*)(src + off + lane * 16),
          (__attribute__((address_space(3))) unsigned int*)((char*)Wt + off),
          16, 0, 0);
    }
  }

  // --- phase 1: s_k for all 8 batches (fp32, coalesced over k=t) while DMA flies
  {
    const float* w = W1T + i * DDm * KKm + t;                 // W1T[i][a][t]
    const float* zj = z_all + ((size_t)j * BB + bgrp * 8) * DDm;
    float ub = b1[i * KKm + t];
    float u[8];
#pragma unroll
    for (int v = 0; v < 8; ++v) u[v] = ub;
#pragma unroll 4
    for (int a = 0; a < DDm; ++a) {
      float wa = w[a * KKm];
#pragma unroll
      for (int v = 0; v < 8; ++v) u[v] = fmaf(wa, zj[v * DDm + a], u[v]);
    }
    float w2v = W2[i * KKm + t];
#pragma unroll
    for (int v = 0; v < 8; ++v) {
      float h = tanhf(u[v]);
      s_lds[v][t] = -2.0f * w2v * h * (1.0f - h * h);
    }
  }
  __syncthreads();   // drains vmcnt too -> Wt + s ready. LAST barrier.

  int wvi = t >> 6, lane = t & 63;
  int g = lane >> 4;              // k-group 0..3
  int lr = lane & 15;             // row-in-tile / col-in-tile
  int bset = wvi >> 1;            // waves 0,1 -> batches 0-3; waves 2,3 -> 4-7
  int m0 = (wvi & 1) * 64;        // row half within batch

  f32x4 acc[4][8];

  for (int bb = 0; bb < 4; ++bb) {
    int bloc = bset * 4 + bb;                    // batch within block (0..7)
    const float* sb = &s_lds[bloc][0];
    float* op = out + (((size_t)pair * BB + bgrp * 8 + bloc) << 14);

#pragma unroll
    for (int mt = 0; mt < 4; ++mt)
#pragma unroll
      for (int nt = 0; nt < 8; ++nt) acc[mt][nt] = (f32x4){0.f, 0.f, 0.f, 0.f};

    for (int kc = 0; kc < 8; ++kc) {
      int kbyte = kc * 64 + g * 16;
      const f32x4* sp = (const f32x4*)&sb[kc * 32 + g * 8];
      f32x4 sA = sp[0], sB = sp[1];
      float sv[8] = {sA[0], sA[1], sA[2], sA[3], sB[0], sB[1], sB[2], sB[3]};

      // A-fragments: s-scaled W rows (this wave's 64 rows)
      bf16x8 afr[4];
#pragma unroll
      for (int mt = 0; mt < 4; ++mt) {
        int row = m0 + mt * 16 + lr;
        u32x4 wq = *(const u32x4*)((const char*)Wt + swz_off(row, kbyte));
        u32x4 aq;
#pragma unroll
        for (int q = 0; q < 4; ++q) {
          float lo = __builtin_bit_cast(float, wq[q] << 16) * sv[2 * q];
          float hi = __builtin_bit_cast(float, wq[q] & 0xffff0000u) * sv[2 * q + 1];
          unsigned int lb = __builtin_bit_cast(unsigned short, (__bf16)lo);
          unsigned int hb = __builtin_bit_cast(unsigned short, (__bf16)hi);
          aq[q] = lb | (hb << 16);   // lo -> low half
        }
        afr[mt] = __builtin_bit_cast(bf16x8, aq);
      }

      // B-fragments: unscaled W rows, stream all 8 column-tiles
#pragma unroll
      for (int nt = 0; nt < 8; ++nt) {
        int row = nt * 16 + lr;
        bf16x8 bfr = __builtin_bit_cast(
            bf16x8, *(const u32x4*)((const char*)Wt + swz_off(row, kbyte)));
#pragma unroll
        for (int mt = 0; mt < 4; ++mt)
          acc[mt][nt] =
              __builtin_amdgcn_mfma_f32_16x16x32_bf16(afr[mt], bfr, acc[mt][nt], 0, 0, 0);
      }
    }

    // --- store (R3 pattern): row = m0 + mt*16 + g*4 + q, col = nt*16 + lr
#pragma unroll
    for (int mt = 0; mt < 4; ++mt) {
      int rbase = m0 + mt * 16 + g * 4;
#pragma unroll
      for (int nt = 0; nt < 8; ++nt) {
        int col = nt * 16 + lr;
#pragma unroll
        for (int q = 0; q < 4; ++q) op[(size_t)(rbase + q) * DDm + col] = acc[mt][nt][q];
      }
    }
  }
}

extern "C" void kernel_launch(void* const* d_in, const int* in_sizes, int n_in,
                              void* d_out, int out_size, void* d_ws, size_t ws_size,
                              hipStream_t stream) {
  const float* z_all = (const float*)d_in[0];
  const float* W1 = (const float*)d_in[1];
  const float* b1 = (const float*)d_in[2];
  const float* W2 = (const float*)d_in[3];
  // b2 (d_in[4]) does not affect the Hessian
  float* out = (float*)d_out;

  unsigned short* Wt_g = (unsigned short*)d_ws;            // 256KB swizzled bf16
  float* W1T = (float*)((char*)d_ws + 262144);             // 512KB fp32 transpose

  prep_kernel<<<32, 256, 0, stream>>>(W1, Wt_g, W1T);
  hess_kernel<<<16 * 32, 256, 0, stream>>>(z_all, b1, W2, Wt_g, W1T, out);
}

// Round 12
// 103.133 us; speedup vs baseline: 1.4054x; 1.4054x over previous
//
#include <hip/hip_runtime.h>
#include <hip/hip_bf16.h>

#define NA 4
#define BB 256
#define DDm 128
#define KKm 256   // hidden = 2*D

typedef __attribute__((ext_vector_type(4))) float f32x4;
typedef __attribute__((ext_vector_type(4))) unsigned int u32x4;
typedef __attribute__((ext_vector_type(8))) short bf16x8;

// RNE float -> bf16 bits
__device__ __forceinline__ unsigned int f2bf(float f) {
  unsigned int bits = __builtin_bit_cast(unsigned int, f);
  unsigned int lsb = (bits >> 16) & 1u;
  return (bits + 0x7fffu + lsb) >> 16;
}

// Swizzled byte offset of element (row a, col k) inside a [128][256] bf16 tile.
// Row stride 512B; XOR bits 4-6 with (a&7): 2-way-max bank aliasing (free, m136).
__device__ __forceinline__ int swz_off(int a, int k2bytes) {
  return ((a << 9) + k2bytes) ^ ((a & 7) << 4);
}

// prep: W1T fp32 [a][k] (coalesced phase-1 reads) + swizzled bf16 W1T tile.
__global__ __launch_bounds__(256) void prep_kernel(const float* __restrict__ W1,
                                                   unsigned short* __restrict__ Wt_g,
                                                   float* __restrict__ W1T) {
  int blk = blockIdx.x;          // 32 blocks = 4 agents x 8 chunks
  int i = blk >> 3;
  int chunk = blk & 7;
  const float* W1i = W1 + i * KKm * DDm;
  char* Wti = (char*)(Wt_g + i * 32768);
  float* W1Ti = W1T + i * DDm * KKm;
  int base = chunk * 4096;
  for (int idx = base + threadIdx.x; idx < base + 4096; idx += 256) {
    int a = idx >> 8;            // 0..127 (z-dim)
    int k = idx & 255;           // 0..255 (hidden)
    float v = W1i[k * DDm + a];
    W1Ti[a * KKm + k] = v;
    *(unsigned short*)(Wti + swz_off(a, k << 1)) = (unsigned short)f2bf(v);
  }
}

// Block = one (i,j) pair x 8 batches. 4 waves, ONE barrier. After it, each
// wave streams 4 independent jobs (one batch x 64 rows x 128 cols each).
// launch_bounds min-waves=1: allocator free to hold acc[4][8] (128 VGPR) +
// temps without spilling (occupancy is LDS-capped at 2 blocks/CU anyway).
__global__ __launch_bounds__(256, 1) void hess_kernel(
    const float* __restrict__ z_all, const float* __restrict__ b1,
    const float* __restrict__ W2, const unsigned short* __restrict__ Wt_g,
    const float* __restrict__ W1T, float* __restrict__ out) {
  __shared__ __align__(16) unsigned short Wt[32768];   // 64KB swizzled bf16 W1_i^T
  __shared__ __align__(16) float s_lds[8][KKm];        // 8KB: per-batch scale vectors

  int t = threadIdx.x;
  int blk = blockIdx.x;
  int pair = blk >> 5;            // 0..15
  int bgrp = blk & 31;            // batch group (8 batches)
  int i = pair >> 2;
  int j = pair & 3;

  if (i == j) {
    // zero 8 batches' diagonal blocks: 512KB contiguous
    f32x4* zp = (f32x4*)(out + (((size_t)pair * BB + bgrp * 8) << 14));
    f32x4 z4 = (f32x4){0.f, 0.f, 0.f, 0.f};
#pragma unroll
    for (int q = 0; q < 128; ++q) zp[q * 256 + t] = z4;
    return;
  }

  // --- issue async staging of W-tile (linear copy; swizzle pre-applied in global)
  {
    int wv = t >> 6, lane = t & 63;
    const char* src = (const char*)(Wt_g + i * 32768);
#pragma unroll
    for (int it = 0; it < 16; ++it) {
      int off = (it * 4 + wv) * 1024;
      __builtin_amdgcn_global_load_lds(
          (const __attribute__((address_space(1))) unsigned int*)(src + off + lane * 16),
          (__attribute__((address_space(3))) unsigned int*)((char*)Wt + off),
          16, 0, 0);
    }
  }

  // --- phase 1: s_k for all 8 batches (fp32, coalesced over k=t) while DMA flies
  {
    const float* w = W1T + i * DDm * KKm + t;                 // W1T[i][a][t]
    const float* zj = z_all + ((size_t)j * BB + bgrp * 8) * DDm;
    float ub = b1[i * KKm + t];
    float u[8];
#pragma unroll
    for (int v = 0; v < 8; ++v) u[v] = ub;
#pragma unroll 4
    for (int a = 0; a < DDm; ++a) {
      float wa = w[a * KKm];
#pragma unroll
      for (int v = 0; v < 8; ++v) u[v] = fmaf(wa, zj[v * DDm + a], u[v]);
    }
    float w2v = W2[i * KKm + t];
#pragma unroll
    for (int v = 0; v < 8; ++v) {
      float h = tanhf(u[v]);
      s_lds[v][t] = -2.0f * w2v * h * (1.0f - h * h);
    }
  }
  __syncthreads();   // drains vmcnt too -> Wt + s ready. LAST barrier.

  int wvi = t >> 6, lane = t & 63;
  int g = lane >> 4;              // k-group 0..3
  int lr = lane & 15;             // row-in-tile / col-in-tile
  int bset = wvi >> 1;            // waves 0,1 -> batches 0-3; waves 2,3 -> 4-7
  int m0 = (wvi & 1) * 64;        // row half within batch

  f32x4 acc[4][8];

  for (int bb = 0; bb < 4; ++bb) {
    int bloc = bset * 4 + bb;                    // batch within block (0..7)
    const float* sb = &s_lds[bloc][0];
    float* op = out + (((size_t)pair * BB + bgrp * 8 + bloc) << 14);

#pragma unroll
    for (int mt = 0; mt < 4; ++mt)
#pragma unroll
      for (int nt = 0; nt < 8; ++nt) acc[mt][nt] = (f32x4){0.f, 0.f, 0.f, 0.f};

    for (int kc = 0; kc < 8; ++kc) {
      int kbyte = kc * 64 + g * 16;
      const f32x4* sp = (const f32x4*)&sb[kc * 32 + g * 8];
      f32x4 sA = sp[0], sB = sp[1];
      float sv[8] = {sA[0], sA[1], sA[2], sA[3], sB[0], sB[1], sB[2], sB[3]};

      // A-fragments: s-scaled W rows (this wave's 64 rows)
      bf16x8 afr[4];
#pragma unroll
      for (int mt = 0; mt < 4; ++mt) {
        int row = m0 + mt * 16 + lr;
        u32x4 wq = *(const u32x4*)((const char*)Wt + swz_off(row, kbyte));
        u32x4 aq;
#pragma unroll
        for (int q = 0; q < 4; ++q) {
          float lo = __builtin_bit_cast(float, wq[q] << 16) * sv[2 * q];
          float hi = __builtin_bit_cast(float, wq[q] & 0xffff0000u) * sv[2 * q + 1];
          unsigned int lb = __builtin_bit_cast(unsigned short, (__bf16)lo);
          unsigned int hb = __builtin_bit_cast(unsigned short, (__bf16)hi);
          aq[q] = lb | (hb << 16);   // lo -> low half
        }
        afr[mt] = __builtin_bit_cast(bf16x8, aq);
      }

      // B-fragments: unscaled W rows, stream all 8 column-tiles
#pragma unroll
      for (int nt = 0; nt < 8; ++nt) {
        int row = nt * 16 + lr;
        bf16x8 bfr = __builtin_bit_cast(
            bf16x8, *(const u32x4*)((const char*)Wt + swz_off(row, kbyte)));
#pragma unroll
        for (int mt = 0; mt < 4; ++mt)
          acc[mt][nt] =
              __builtin_amdgcn_mfma_f32_16x16x32_bf16(afr[mt], bfr, acc[mt][nt], 0, 0, 0);
      }
    }

    // --- store (R3 pattern): row = m0 + mt*16 + g*4 + q, col = nt*16 + lr
#pragma unroll
    for (int mt = 0; mt < 4; ++mt) {
      int rbase = m0 + mt * 16 + g * 4;
#pragma unroll
      for (int nt = 0; nt < 8; ++nt) {
        int col = nt * 16 + lr;
#pragma unroll
        for (int q = 0; q < 4; ++q) op[(size_t)(rbase + q) * DDm + col] = acc[mt][nt][q];
      }
    }
  }
}

extern "C" void kernel_launch(void* const* d_in, const int* in_sizes, int n_in,
                              void* d_out, int out_size, void* d_ws, size_t ws_size,
                              hipStream_t stream) {
  const float* z_all = (const float*)d_in[0];
  const float* W1 = (const float*)d_in[1];
  const float* b1 = (const float*)d_in[2];
  const float* W2 = (const float*)d_in[3];
  // b2 (d_in[4]) does not affect the Hessian
  float* out = (float*)d_out;

  unsigned short* Wt_g = (unsigned short*)d_ws;            // 256KB swizzled bf16
  float* W1T = (float*)((char*)d_ws + 262144);             // 512KB fp32 transpose

  prep_kernel<<<32, 256, 0, stream>>>(W1, Wt_g, W1T);
  hess_kernel<<<16 * 32, 256, 0, stream>>>(z_all, b1, W2, Wt_g, W1T, out);
}

// Round 13
// 70.119 us; speedup vs baseline: 2.0671x; 1.4708x over previous
//
#include <hip/hip_runtime.h>
#include <hip/hip_bf16.h>

#define NA 4
#define BB 256
#define DDm 128
#define KKm 256   // hidden = 2*D

typedef __attribute__((ext_vector_type(4))) float f32x4;
typedef __attribute__((ext_vector_type(4))) unsigned int u32x4;
typedef __attribute__((ext_vector_type(8))) short bf16x8;

// RNE float -> bf16 bits
__device__ __forceinline__ unsigned int f2bf(float f) {
  unsigned int bits = __builtin_bit_cast(unsigned int, f);
  unsigned int lsb = (bits >> 16) & 1u;
  return (bits + 0x7fffu + lsb) >> 16;
}

// Swizzled byte offset of element (row a, col k) inside a [128][256] bf16 tile.
// Row stride 512B; XOR bits 4-6 with (a&7): conflict-free b128 column reads.
__device__ __forceinline__ int swz_off(int a, int k2bytes) {
  return ((a << 9) + k2bytes) ^ ((a & 7) << 4);
}

// prep: W1T fp32 [a][k] (coalesced phase-1 reads) + swizzled bf16 W1T tile.
__global__ __launch_bounds__(256) void prep_kernel(const float* __restrict__ W1,
                                                   unsigned short* __restrict__ Wt_g,
                                                   float* __restrict__ W1T) {
  int blk = blockIdx.x;          // 32 blocks = 4 agents x 8 chunks
  int i = blk >> 3;
  int chunk = blk & 7;
  const float* W1i = W1 + i * KKm * DDm;
  char* Wti = (char*)(Wt_g + i * 32768);
  float* W1Ti = W1T + i * DDm * KKm;
  int base = chunk * 4096;
  for (int idx = base + threadIdx.x; idx < base + 4096; idx += 256) {
    int a = idx >> 8;            // 0..127 (z-dim)
    int k = idx & 255;           // 0..255 (hidden)
    float v = W1i[k * DDm + a];
    W1Ti[a * KKm + k] = v;
    *(unsigned short*)(Wti + swz_off(a, k << 1)) = (unsigned short)f2bf(v);
  }
}

// Block = one (i,j) pair x 16 batches, 512 threads (8 waves). ONE barrier.
// After it, each wave streams 8 independent 32-row chunk-jobs (2 batches x 4
// chunks) with alternating acc sets (R10 structure, unchanged inner loop).
// 80KB LDS -> 2 blocks/CU -> 16 waves/CU (4/SIMD): store issue from some
// waves overlays kc-loops of others -> continuous write stream.
__global__ __launch_bounds__(512, 2) void hess_kernel(
    const float* __restrict__ z_all, const float* __restrict__ b1,
    const float* __restrict__ W2, const unsigned short* __restrict__ Wt_g,
    const float* __restrict__ W1T, float* __restrict__ out) {
  __shared__ __align__(16) unsigned short Wt[32768];   // 64KB swizzled bf16 W1_i^T
  __shared__ __align__(16) float s_lds[16][KKm];       // 16KB: per-batch scale vectors

  int t = threadIdx.x;
  int blk = blockIdx.x;
  int pair = blk >> 4;            // 0..15
  int bgrp = blk & 15;            // batch group (16 batches)
  int i = pair >> 2;
  int j = pair & 3;

  if (i == j) {
    // zero 16 batches' diagonal blocks: 1MB contiguous
    f32x4* zp = (f32x4*)(out + (((size_t)pair * BB + bgrp * 16) << 14));
    f32x4 z4 = (f32x4){0.f, 0.f, 0.f, 0.f};
#pragma unroll
    for (int q = 0; q < 128; ++q) zp[q * 512 + t] = z4;
    return;
  }

  int wvi = t >> 6, lane = t & 63;

  // --- issue async staging of W-tile (linear copy; swizzle pre-applied in global)
  {
    const char* src = (const char*)(Wt_g + i * 32768);
#pragma unroll
    for (int it = 0; it < 8; ++it) {
      int off = (it * 8 + wvi) * 1024;
      __builtin_amdgcn_global_load_lds(
          (const __attribute__((address_space(1))) unsigned int*)(src + off + lane * 16),
          (__attribute__((address_space(3))) unsigned int*)((char*)Wt + off),
          16, 0, 0);
    }
  }

  // --- phase 1: s_k for 16 batches (threads 0-255: batches 0-7; 256-511: 8-15)
  {
    int k = t & 255;
    int oct = t >> 8;
    const float* w = W1T + i * DDm * KKm + k;                 // W1T[i][a][k]
    const float* zj = z_all + ((size_t)j * BB + bgrp * 16 + oct * 8) * DDm;
    float ub = b1[i * KKm + k];
    float u[8];
#pragma unroll
    for (int v = 0; v < 8; ++v) u[v] = ub;
#pragma unroll 4
    for (int a = 0; a < DDm; ++a) {
      float wa = w[a * KKm];
#pragma unroll
      for (int v = 0; v < 8; ++v) u[v] = fmaf(wa, zj[v * DDm + a], u[v]);
    }
    float w2v = W2[i * KKm + k];
#pragma unroll
    for (int v = 0; v < 8; ++v) {
      float h = tanhf(u[v]);
      s_lds[oct * 8 + v][k] = -2.0f * w2v * h * (1.0f - h * h);
    }
  }
  __syncthreads();   // drains vmcnt too -> Wt + s ready. LAST barrier.

  int g = lane >> 4;              // k-group 0..3
  int lr = lane & 15;             // row-in-tile / col-in-tile

  f32x4 accA[2][8], accB[2][8];

  // One 32-row chunk: full kc-loop + store (R10 pattern, unchanged).
  auto do_chunk = [&](f32x4 (&acc)[2][8], int rowbase, const float* sb, float* op) {
#pragma unroll
    for (int mt = 0; mt < 2; ++mt)
#pragma unroll
      for (int nt = 0; nt < 8; ++nt) acc[mt][nt] = (f32x4){0.f, 0.f, 0.f, 0.f};

    for (int kc = 0; kc < 8; ++kc) {
      int kbyte = kc * 64 + g * 16;
      const f32x4* sp = (const f32x4*)&sb[kc * 32 + g * 8];
      f32x4 sA = sp[0], sB = sp[1];
      float sv[8] = {sA[0], sA[1], sA[2], sA[3], sB[0], sB[1], sB[2], sB[3]};

      bf16x8 afr[2];
#pragma unroll
      for (int mt = 0; mt < 2; ++mt) {
        int row = rowbase + mt * 16 + lr;
        u32x4 wq = *(const u32x4*)((const char*)Wt + swz_off(row, kbyte));
        u32x4 aq;
#pragma unroll
        for (int q = 0; q < 4; ++q) {
          float lo = __builtin_bit_cast(float, wq[q] << 16) * sv[2 * q];
          float hi = __builtin_bit_cast(float, wq[q] & 0xffff0000u) * sv[2 * q + 1];
          unsigned int lb = __builtin_bit_cast(unsigned short, (__bf16)lo);
          unsigned int hb = __builtin_bit_cast(unsigned short, (__bf16)hi);
          aq[q] = lb | (hb << 16);   // lo -> low half
        }
        afr[mt] = __builtin_bit_cast(bf16x8, aq);
      }

#pragma unroll
      for (int nt = 0; nt < 8; ++nt) {
        int row = nt * 16 + lr;
        bf16x8 bfr = __builtin_bit_cast(
            bf16x8, *(const u32x4*)((const char*)Wt + swz_off(row, kbyte)));
        acc[0][nt] = __builtin_amdgcn_mfma_f32_16x16x32_bf16(afr[0], bfr, acc[0][nt], 0, 0, 0);
        acc[1][nt] = __builtin_amdgcn_mfma_f32_16x16x32_bf16(afr[1], bfr, acc[1][nt], 0, 0, 0);
      }
    }

#pragma unroll
    for (int mt = 0; mt < 2; ++mt) {
      int rbase = rowbase + mt * 16 + g * 4;
#pragma unroll
      for (int nt = 0; nt < 8; ++nt) {
        int col = nt * 16 + lr;
#pragma unroll
        for (int q = 0; q < 4; ++q) op[(size_t)(rbase + q) * DDm + col] = acc[mt][nt][q];
      }
    }
  };

  // Wave handles 2 batches x 4 chunks = 8 jobs, alternating acc sets.
  for (int bb = 0; bb < 2; ++bb) {
    int bloc = wvi * 2 + bb;                     // batch within block (0..15)
    const float* sb = &s_lds[bloc][0];
    float* op = out + (((size_t)pair * BB + bgrp * 16 + bloc) << 14);
    do_chunk(accA, 0, sb, op);
    do_chunk(accB, 32, sb, op);
    do_chunk(accA, 64, sb, op);
    do_chunk(accB, 96, sb, op);
  }
}

extern "C" void kernel_launch(void* const* d_in, const int* in_sizes, int n_in,
                              void* d_out, int out_size, void* d_ws, size_t ws_size,
                              hipStream_t stream) {
  const float* z_all = (const float*)d_in[0];
  const float* W1 = (const float*)d_in[1];
  const float* b1 = (const float*)d_in[2];
  const float* W2 = (const float*)d_in[3];
  // b2 (d_in[4]) does not affect the Hessian
  float* out = (float*)d_out;

  unsigned short* Wt_g = (unsigned short*)d_ws;            // 256KB swizzled bf16
  float* W1T = (float*)((char*)d_ws + 262144);             // 512KB fp32 transpose

  prep_kernel<<<32, 256, 0, stream>>>(W1, Wt_g, W1T);
  hess_kernel<<<16 * 16, 512, 0, stream>>>(z_all, b1, W2, Wt_g, W1T, out);
}